// Round 12
// baseline (379.775 us; speedup 1.0000x reference)
//
#include <hip/hip_runtime.h>
#include <hip/hip_fp16.h>
#include <math.h>

#define BB 2
#define SS 2048
#define EE 1024
#define HH 16
#define DD 64
#define YAT_EPS 1e-5f
#define RR (BB * HH * SS)   // 65536 attention rows

typedef __attribute__((ext_vector_type(8))) short bf16x8;
typedef __attribute__((ext_vector_type(4))) short short4v;
typedef __attribute__((ext_vector_type(4))) float f32x4;
#define MFMA16(a, b, c) __builtin_amdgcn_mfma_f32_16x16x32_bf16((a), (b), (c), 0, 0, 0)

#if __has_builtin(__builtin_amdgcn_exp2f)
#define EXP2(x) __builtin_amdgcn_exp2f(x)
#else
#define EXP2(x) exp2f(x)
#endif
#if __has_builtin(__builtin_amdgcn_rcpf)
#define RCPF(x) __builtin_amdgcn_rcpf(x)
#else
#define RCPF(x) (1.0f / (x))
#endif

__device__ __forceinline__ unsigned short f2bf(float x) {
    unsigned int u = __float_as_uint(x);
    u += 0x7FFFu + ((u >> 16) & 1u);   // RNE
    return (unsigned short)(u >> 16);
}
__device__ __forceinline__ float bf2f(unsigned short h) {
    return __uint_as_float(((unsigned int)h) << 16);
}
// truncating fp32->bf16 (1 op; P in [0,1], bias ~0.1% — renorm-safe)
__device__ __forceinline__ short f2bf_t(float x) {
    return (short)(__float_as_uint(x) >> 16);
}

__device__ __forceinline__ void async_ld16(void* lds, const void* g) {
    __builtin_amdgcn_global_load_lds(
        (const __attribute__((address_space(1))) unsigned int*)g,
        (__attribute__((address_space(3))) unsigned int*)lds, 16, 0, 0);
}

// fp32 -> bf16 hi/lo split (grid covers n/4 float4s exactly)
__global__ __launch_bounds__(256) void split_f32(const float* __restrict__ in,
                                                 unsigned short* __restrict__ hi,
                                                 unsigned short* __restrict__ lo,
                                                 int n4) {
    int i = blockIdx.x * 256 + threadIdx.x;
    if (i >= n4) return;
    float4 v = ((const float4*)in)[i];
    ushort4 h, l;
    h.x = f2bf(v.x); l.x = f2bf(v.x - bf2f(h.x));
    h.y = f2bf(v.y); l.y = f2bf(v.y - bf2f(h.y));
    h.z = f2bf(v.z); l.z = f2bf(v.z - bf2f(h.z));
    h.w = f2bf(v.w); l.w = f2bf(v.w - bf2f(h.w));
    ((ushort4*)hi)[i] = h;
    ((ushort4*)lo)[i] = l;
}

// fused hi/lo split of the four weight matrices; lo only needed for Wq,Wk
__global__ __launch_bounds__(256) void split_w4(
        const float* __restrict__ Wq, const float* __restrict__ Wk,
        const float* __restrict__ Wv, const float* __restrict__ Wo,
        unsigned short* __restrict__ Whi, unsigned short* __restrict__ Wlo,
        unsigned short* __restrict__ Wohi) {
    int i = blockIdx.x * 256 + threadIdx.x;      // < EE*EE/4
    int y = blockIdx.y;
    const float* src = y == 0 ? Wq : y == 1 ? Wk : y == 2 ? Wv : Wo;
    unsigned short* hi = y < 3 ? Whi + (size_t)y * EE * EE : Wohi;
    float4 v = ((const float4*)src)[i];
    ushort4 h;
    h.x = f2bf(v.x); h.y = f2bf(v.y); h.z = f2bf(v.z); h.w = f2bf(v.w);
    ((ushort4*)hi)[i] = h;
    if (y < 2) {
        unsigned short* lo = Wlo + (size_t)y * EE * EE;
        ushort4 l;
        l.x = f2bf(v.x - bf2f(h.x));
        l.y = f2bf(v.y - bf2f(h.y));
        l.z = f2bf(v.z - bf2f(h.z));
        l.w = f2bf(v.w - bf2f(h.w));
        ((ushort4*)lo)[i] = l;
    }
}

// bf16 MFMA GEMM, PASSES=3 (hi/lo Markidis) or 1 (plain bf16).
// C[M,N] = A[M,K] @ B[N,K]^T + bias.
// MODE 0: fp32 out + bias(bq).
// MODE 1: q/k epilogue (N=2048): bf16 hi(+lo for q) [B,H,S,D] + fp32 norms.
// MODE 2: v epilogue (N=1024): bf16 [B,H,S,D], bias in bv.
template <int MODE, int PASSES>
__global__ __launch_bounds__(256, 2) void gemm3p(
        const unsigned short* __restrict__ Ahi, const unsigned short* __restrict__ Alo,
        const unsigned short* __restrict__ Bhi, const unsigned short* __restrict__ Blo,
        const float* __restrict__ bq, const float* __restrict__ bk,
        const float* __restrict__ bv,
        float* __restrict__ Cf,
        unsigned short* __restrict__ qhi, unsigned short* __restrict__ qlo,
        unsigned short* __restrict__ khi,
        unsigned short* __restrict__ v_sd,
        float* __restrict__ sqn, float* __restrict__ skn,
        int M, int N, int K) {
    __shared__ __align__(16) unsigned short LA_hi[128 * 32];
    __shared__ __align__(16) unsigned short LA_lo[128 * 32];
    __shared__ __align__(16) unsigned short LB_hi[128 * 32];
    __shared__ __align__(16) unsigned short LB_lo[128 * 32];

    const int t = threadIdx.x;
    const int w = t >> 6, lane = t & 63;
    const int quad = lane >> 4, lr = lane & 15;
    const int wy = w & 1, wx = w >> 1;
    const int m0 = blockIdx.y * 128, n0 = blockIdx.x * 128;

    const unsigned short* gsrc = nullptr;
    unsigned short* ldst = nullptr;
    if (w == 0)      { gsrc = Ahi + (size_t)m0 * K; ldst = LA_hi; }
    else if (w == 2) { gsrc = Bhi + (size_t)n0 * K; ldst = LB_hi; }
    else if (PASSES == 3 && w == 1) { gsrc = Alo + (size_t)m0 * K; ldst = LA_lo; }
    else if (PASSES == 3 && w == 3) { gsrc = Blo + (size_t)n0 * K; ldst = LB_lo; }
    const unsigned short* gl = gsrc ? gsrc + (size_t)(lane >> 2) * K + (lane & 3) * 8
                                    : nullptr;

    f32x4 acc[4][4];
    #pragma unroll
    for (int i = 0; i < 4; ++i)
        #pragma unroll
        for (int j = 0; j < 4; ++j)
            acc[i][j] = (f32x4){0.f, 0.f, 0.f, 0.f};

    for (int k0 = 0; k0 < K; k0 += 32) {
        __syncthreads();
        if (gl) {
            #pragma unroll
            for (int i = 0; i < 8; ++i)
                async_ld16(ldst + i * 512, gl + (size_t)i * 16 * K + k0);
        }
        __syncthreads();
        bf16x8 ah[4], al[4], bh_[4], bl_[4];
        #pragma unroll
        for (int i = 0; i < 4; ++i) {
            ah[i]  = *(const bf16x8*)&LA_hi[(wy * 64 + i * 16 + lr) * 32 + quad * 8];
            bh_[i] = *(const bf16x8*)&LB_hi[(wx * 64 + i * 16 + lr) * 32 + quad * 8];
            if (PASSES == 3) {
                al[i]  = *(const bf16x8*)&LA_lo[(wy * 64 + i * 16 + lr) * 32 + quad * 8];
                bl_[i] = *(const bf16x8*)&LB_lo[(wx * 64 + i * 16 + lr) * 32 + quad * 8];
            }
        }
        #pragma unroll
        for (int mg = 0; mg < 4; ++mg)
            #pragma unroll
            for (int ns = 0; ns < 4; ++ns) {
                f32x4 a = acc[mg][ns];
                a = MFMA16(ah[mg], bh_[ns], a);
                if (PASSES == 3) {
                    a = MFMA16(ah[mg], bl_[ns], a);
                    a = MFMA16(al[mg], bh_[ns], a);
                }
                acc[mg][ns] = a;
            }
    }

    const int ng = n0 + wx * 64;
    if (MODE == 0) {
        float bias_v[4];
        #pragma unroll
        for (int ns = 0; ns < 4; ++ns) bias_v[ns] = bq[ng + ns * 16 + lr];
        #pragma unroll
        for (int mg = 0; mg < 4; ++mg)
            #pragma unroll
            for (int r = 0; r < 4; ++r) {
                int m = m0 + wy * 64 + mg * 16 + quad * 4 + r;
                #pragma unroll
                for (int ns = 0; ns < 4; ++ns)
                    Cf[(size_t)m * N + ng + ns * 16 + lr] = acc[mg][ns][r] + bias_v[ns];
            }
    } else {
        const int path = MODE == 1 ? (ng >> 10) : 2;   // 0=q 1=k 2=v
        const int c = MODE == 1 ? (ng & 1023) : ng;
        const int h = c >> 6;
        const float* bias = path == 0 ? bq : path == 1 ? bk : bv;
        unsigned short* hi_p = path == 0 ? qhi : path == 1 ? khi : v_sd;
        float* nrm = path == 0 ? sqn : skn;
        float bias_v[4];
        #pragma unroll
        for (int ns = 0; ns < 4; ++ns) bias_v[ns] = bias[c + ns * 16 + lr];
        #pragma unroll
        for (int mg = 0; mg < 4; ++mg)
            #pragma unroll
            for (int r = 0; r < 4; ++r) {
                int m = m0 + wy * 64 + mg * 16 + quad * 4 + r;
                int b = m >> 11, s = m & (SS - 1);
                size_t base = ((size_t)(b * HH + h) * SS + s) * DD;
                float v4[4];
                #pragma unroll
                for (int ns = 0; ns < 4; ++ns) v4[ns] = acc[mg][ns][r] + bias_v[ns];
                if (path < 2) {
                    float pn = v4[0] * v4[0] + v4[1] * v4[1] + v4[2] * v4[2] + v4[3] * v4[3];
                    #pragma unroll
                    for (int off = 1; off < 16; off <<= 1) pn += __shfl_xor(pn, off);
                    if (lr == 0) nrm[(size_t)(b * HH + h) * SS + s] = pn;
                    #pragma unroll
                    for (int ns = 0; ns < 4; ++ns) {
                        unsigned short hv = f2bf(v4[ns]);
                        hi_p[base + ns * 16 + lr] = hv;
                        if (path == 0)
                            qlo[base + ns * 16 + lr] = f2bf(v4[ns] - bf2f(hv));
                    }
                } else {
                    #pragma unroll
                    for (int ns = 0; ns < 4; ++ns)
                        hi_p[base + ns * 16 + lr] = f2bf(v4[ns]);
                }
            }
    }
}

// [bh][s][d] -> [bh][d][s] bf16 transpose, 64x64 LDS tiles
__global__ __launch_bounds__(256) void transpose_v(const unsigned short* __restrict__ v_sd,
                                                   unsigned short* __restrict__ vt) {
    __shared__ unsigned short T[64][65];
    const int t = threadIdx.x;
    const int bh = blockIdx.y, s0 = blockIdx.x * 64;
    {
        int sl = t >> 2, d4 = (t & 3) * 16;
        const unsigned short* src = &v_sd[((size_t)bh * SS + s0 + sl) * DD + d4];
        bf16x8 a = *(const bf16x8*)src;
        bf16x8 b = *(const bf16x8*)(src + 8);
        #pragma unroll
        for (int j = 0; j < 8; ++j) {
            T[sl][d4 + j] = (unsigned short)a[j];
            T[sl][d4 + 8 + j] = (unsigned short)b[j];
        }
    }
    __syncthreads();
    {
        int dl = t >> 2, s4 = (t & 3) * 16;
        bf16x8 a, b;
        #pragma unroll
        for (int j = 0; j < 8; ++j) {
            a[j] = (short)T[s4 + j][dl];
            b[j] = (short)T[s4 + 8 + j][dl];
        }
        unsigned short* dst = &vt[((size_t)bh * DD + dl) * SS + s0 + s4];
        *(bf16x8*)dst = a;
        *(bf16x8*)(dst + 8) = b;
    }
}

// MFMA flash attention v6: SOFTWARE-PIPELINED k-tiles. Round-11 counters
// showed cutting MFMA/LDS work didn't cut time -> latency-bound on the serial
// chain (ds_read K -> QK MFMA -> max -> exp2 -> sum -> P pack -> PV). Now
// QK(it+1) issues BEFORE softmax(it)+PV(it): the two chains are independent,
// so MFMA fills the softmax bubble and vice versa. K dbuf supports the
// prefetch-2 schedule: barrier(it) drains stage of K[it+1] AND (via the
// compiler's waitcnt-before-barrier) all QK(it) LDS reads of the buffer that
// K[it+2] then overwrites. Extra acc set = +16 AGPR; ~124 unified regs,
// (256,3) cap 170 -> no spills.
__global__ __launch_bounds__(256, 3) void yat_attn_mfma(
        const unsigned short* __restrict__ qhi, const unsigned short* __restrict__ qlo,
        const unsigned short* __restrict__ khi,
        const unsigned short* __restrict__ vt,
        const float* __restrict__ sqn, const float* __restrict__ skn,
        const float* __restrict__ alphap,
        __half* __restrict__ Opart, float2* __restrict__ mlpart) {
    __shared__ __align__(16) unsigned short Ks[2][4096];        // [dbuf] khi, 16KB
    __shared__ __align__(16) unsigned short Ps[2][4][16 * 68];  // [dbuf][wave] 17.4KB

    const int t = threadIdx.x;
    const int w = t >> 6, lane = t & 63;
    const int quad = lane >> 4, lr = lane & 15;
    const int qt = blockIdx.x, bh = blockIdx.y, z = blockIdx.z;
    const int row0 = qt * 64 + w * 16;
    const float cscale = powf(sqrtf((float)DD) / log1pf((float)DD), alphap[0])
                         * 1.4426950408889634f;

    // persistent Q fragments (B-operand: lane holds q-col = lr)
    bf16x8 qh[2], ql[2];
    #pragma unroll
    for (int kd = 0; kd < 2; ++kd) {
        size_t o = ((size_t)bh * SS + row0 + lr) * DD + kd * 32 + quad * 8;
        qh[kd] = *(const bf16x8*)&qhi[o];
        ql[kd] = *(const bf16x8*)&qlo[o];
    }
    const float sqe = sqn[(size_t)bh * SS + row0 + lr] + YAT_EPS;

    // staging: wave w stages rows [w*16,w*16+16) of khi; XOR-swizzled chunks
    const int lrow = lane >> 3;
    const int lofs = lrow * 64 + (((lane & 7) ^ (lrow & 7)) << 3);
    const int sw = lr & 7;

    float m_r = -INFINITY, l_r = 0.f;
    f32x4 O[4];
    #pragma unroll
    for (int nd = 0; nd < 4; ++nd) O[nd] = (f32x4){0.f, 0.f, 0.f, 0.f};

    const int kt0 = z * 16;
    const size_t khi_base = (size_t)bh * SS * 64 + (size_t)w * 16 * 64 + lofs;
    const size_t skn_base = (size_t)bh * SS + quad * 4;

    // ---- prologue: stage K[0]; after barrier, stage K[1] and compute QK(0)
    #pragma unroll
    for (int i2 = 0; i2 < 2; ++i2)
        async_ld16(&Ks[0][w * 1024 + i2 * 512],
                   khi + khi_base + (size_t)(kt0 + 0) * 64 * 64 + i2 * 512);
    __syncthreads();   // K[0] staged
    #pragma unroll
    for (int i2 = 0; i2 < 2; ++i2)
        async_ld16(&Ks[1][w * 1024 + i2 * 512],
                   khi + khi_base + (size_t)(kt0 + 1) * 64 * 64 + i2 * 512);

    f32x4 accA[4], sk4A[4];
    #pragma unroll
    for (int st = 0; st < 4; ++st) {
        const int rbase = (st * 16 + lr) * 64;
        bf16x8 kh0 = *(const bf16x8*)&Ks[0][rbase + ((quad    ) ^ sw) * 8];
        bf16x8 kh1 = *(const bf16x8*)&Ks[0][rbase + ((quad + 4) ^ sw) * 8];
        sk4A[st] = *(const f32x4*)&skn[skn_base + (kt0 + 0) * 64 + st * 16];
        f32x4 a = (f32x4){0.f, 0.f, 0.f, 0.f};
        a = MFMA16(kh0, qh[0], a);
        a = MFMA16(kh1, qh[1], a);
        a = MFMA16(kh0, ql[0], a);
        a = MFMA16(kh1, ql[1], a);
        accA[st] = a;
    }

    for (int it = 0; it < 16; ++it) {
        const int kt = kt0 + it;
        const int p = it & 1;
        __syncthreads();   // drains stage of K[it+1] into Ks[p^1]; QK(it) reads done
        if (it + 2 < 16) {   // prefetch K[it+2] into Ks[p] (K[it] fully consumed)
            const size_t gb = khi_base + (size_t)(kt + 2) * 64 * 64;
            #pragma unroll
            for (int i2 = 0; i2 < 2; ++i2)
                async_ld16(&Ks[p][w * 1024 + i2 * 512], khi + gb + i2 * 512);
        }
        // ---- QK(it+1) from Ks[p^1] — independent of softmax(it) below ----
        f32x4 accB[4], sk4B[4];
        if (it + 1 < 16) {
            const unsigned short* kb = Ks[p ^ 1];
            #pragma unroll
            for (int st = 0; st < 4; ++st) {
                const int rbase = (st * 16 + lr) * 64;
                bf16x8 kh0 = *(const bf16x8*)&kb[rbase + ((quad    ) ^ sw) * 8];
                bf16x8 kh1 = *(const bf16x8*)&kb[rbase + ((quad + 4) ^ sw) * 8];
                sk4B[st] = *(const f32x4*)&skn[skn_base + (kt + 1) * 64 + st * 16];
                f32x4 a = (f32x4){0.f, 0.f, 0.f, 0.f};
                a = MFMA16(kh0, qh[0], a);
                a = MFMA16(kh1, qh[1], a);
                a = MFMA16(kh0, ql[0], a);
                a = MFMA16(kh1, ql[1], a);
                accB[st] = a;
            }
        }
        // ---- V fragments for tile it (latency covered by softmax below) ----
        bf16x8 vf[4][2];
        #pragma unroll
        for (int nd = 0; nd < 4; ++nd)
            #pragma unroll
            for (int kk = 0; kk < 2; ++kk)
                vf[nd][kk] = *(const bf16x8*)&vt[((size_t)bh * DD + nd * 16 + lr) * SS
                                                 + kt * 64 + kk * 32 + quad * 8];
        // ---- softmax(it) on accA (exp2 domain, in place) ----
        unsigned short* myP = Ps[p][w];
        float mx = -INFINITY;
        #pragma unroll
        for (int st = 0; st < 4; ++st)
            #pragma unroll
            for (int r = 0; r < 4; ++r) {
                float qk = accA[st][r];
                float d = sqe + sk4A[st][r] - 2.f * qk;
                float s = qk * qk * cscale * RCPF(d);
                accA[st][r] = s;
                mx = fmaxf(mx, s);
            }
        mx = fmaxf(mx, __shfl_xor(mx, 16));
        mx = fmaxf(mx, __shfl_xor(mx, 32));
        float mnew = fmaxf(m_r, mx);
        float aa = EXP2(m_r - mnew);
        m_r = mnew;
        float rs = 0.f;
        #pragma unroll
        for (int st = 0; st < 4; ++st)
            #pragma unroll
            for (int r = 0; r < 4; ++r) {
                float e = EXP2(accA[st][r] - mnew);
                accA[st][r] = e;
                rs += e;
            }
        rs += __shfl_xor(rs, 16);
        rs += __shfl_xor(rs, 32);
        l_r = l_r * aa + rs;
        #pragma unroll
        for (int st = 0; st < 4; ++st) {
            short4v pv;
            pv[0] = f2bf_t(accA[st][0]);
            pv[1] = f2bf_t(accA[st][1]);
            pv[2] = f2bf_t(accA[st][2]);
            pv[3] = f2bf_t(accA[st][3]);
            *(short4v*)&myP[lr * 68 + st * 16 + quad * 4] = pv;
        }
        float al_[4];
        #pragma unroll
        for (int r = 0; r < 4; ++r) al_[r] = __shfl(aa, quad * 4 + r);
        #pragma unroll
        for (int nd = 0; nd < 4; ++nd)
            #pragma unroll
            for (int r = 0; r < 4; ++r)
                O[nd][r] *= al_[r];
        // ---- PV(it): A = P from LDS, B = V^T ----
        bf16x8 pf[2];
        #pragma unroll
        for (int kk = 0; kk < 2; ++kk)
            pf[kk] = *(const bf16x8*)&myP[lr * 68 + kk * 32 + quad * 8];
        #pragma unroll
        for (int nd = 0; nd < 4; ++nd)
            #pragma unroll
            for (int kk = 0; kk < 2; ++kk)
                O[nd] = MFMA16(pf[kk], vf[nd][kk], O[nd]);
        // ---- rotate pipeline ----
        #pragma unroll
        for (int st = 0; st < 4; ++st) { accA[st] = accB[st]; sk4A[st] = sk4B[st]; }
    }
    // ---- epilogue: write fp16 partial O + (m,l) ----
    if (quad == 0)
        mlpart[(size_t)z * RR + (size_t)bh * SS + row0 + lr] = make_float2(m_r, l_r);
    #pragma unroll
    for (int r = 0; r < 4; ++r) {
        size_t rowg = (size_t)bh * SS + row0 + quad * 4 + r;
        #pragma unroll
        for (int nd = 0; nd < 4; ++nd)
            Opart[((size_t)z * RR + rowg) * DD + nd * 16 + lr] =
                __float2half(O[nd][r]);
    }
}

// merge K-split halves; write ctx bf16 (hi only — O-proj is plain bf16)
__global__ __launch_bounds__(256) void combine_attn(
        const __half* __restrict__ Opart, const float2* __restrict__ mlpart,
        unsigned short* __restrict__ ctxhi) {
    int tid = blockIdx.x * 256 + threadIdx.x;
    int row = tid >> 4, c4 = (tid & 15) * 4;
    float2 ml0 = mlpart[row];
    float2 ml1 = mlpart[RR + row];
    float ms = fmaxf(ml0.x, ml1.x);
    float a0 = EXP2(ml0.x - ms), a1 = EXP2(ml1.x - ms);
    float inv = RCPF(ml0.y * a0 + ml1.y * a1);
    a0 *= inv; a1 *= inv;
    const __half* p0 = Opart + (size_t)row * DD + c4;
    const __half* p1 = p0 + (size_t)RR * DD;
    int bh = row >> 11, s = row & (SS - 1);
    int b = bh >> 4, h = bh & 15;
    size_t idx = ((size_t)b * SS + s) * EE + h * DD + c4;
    ushort4 hv;
    unsigned short* hp = (unsigned short*)&hv;
    #pragma unroll
    for (int j = 0; j < 4; ++j) {
        float o = __half2float(p0[j]) * a0 + __half2float(p1[j]) * a1;
        hp[j] = f2bf(o);
    }
    *(ushort4*)&ctxhi[idx] = hv;
}

extern "C" void kernel_launch(void* const* d_in, const int* in_sizes, int n_in,
                              void* d_out, int out_size, void* d_ws, size_t ws_size,
                              hipStream_t stream) {
    const float* x     = (const float*)d_in[0];
    const float* Wq    = (const float*)d_in[1];
    const float* bq    = (const float*)d_in[2];
    const float* Wk    = (const float*)d_in[3];
    const float* bk    = (const float*)d_in[4];
    const float* Wv    = (const float*)d_in[5];
    const float* bv    = (const float*)d_in[6];
    const float* Wo    = (const float*)d_in[7];
    const float* bo    = (const float*)d_in[8];
    const float* alpha = (const float*)d_in[9];
    float* out = (float*)d_out;
    char* ws = (char*)d_ws;

    const int M = BB * SS;                 // 4096
    const size_t MB = 1u << 20;
    unsigned short* xhi  = (unsigned short*)(ws + 0 * MB);   // later: ctxhi
    unsigned short* xlo  = (unsigned short*)(ws + 8 * MB);
    unsigned short* Whi  = (unsigned short*)(ws + 16 * MB);  // 6 MB (qkv concat)
    unsigned short* Wlo  = (unsigned short*)(ws + 22 * MB);  // 4 MB used (q,k)
    unsigned short* vt   = (unsigned short*)(ws + 16 * MB);  // reuses dead Whi area
    float2* mlpart       = (float2*)(ws + 24 * MB);          // 1 MB
    unsigned short* Wohi = (unsigned short*)(ws + 28 * MB);
    unsigned short* qhi  = (unsigned short*)(ws + 32 * MB);
    unsigned short* qlo  = (unsigned short*)(ws + 40 * MB);
    unsigned short* khi  = (unsigned short*)(ws + 48 * MB);
    unsigned short* v_sd = (unsigned short*)(ws + 64 * MB);  // dead after transpose
    __half* Opart        = (__half*)(ws + 64 * MB);          // 16 MB (reuses v_sd)
    float* sqn = (float*)(ws + 80 * MB);
    float* skn = (float*)(ws + 80 * MB + 256 * 1024);
    unsigned short* ctxhi = xhi;

    const int nX = M * EE / 4, nW = EE * EE / 4;
    split_f32<<<nX / 256, 256, 0, stream>>>(x, xhi, xlo, nX);
    split_w4<<<dim3(nW / 256, 4), 256, 0, stream>>>(Wq, Wk, Wv, Wo, Whi, Wlo, Wohi);

    // Q/K projections: 3-pass (K=1024 — 2-pass would inject ~0.03 into q/k)
    gemm3p<1, 3><<<dim3(2 * EE / 128, M / 128), 256, 0, stream>>>(
        xhi, xlo, Whi, Wlo, bq, bk, nullptr, nullptr,
        qhi, qlo, khi, nullptr, sqn, skn, M, 2 * EE, EE);
    // V projection: plain bf16 (consumed as bf16 anyway)
    gemm3p<2, 1><<<dim3(EE / 128, M / 128), 256, 0, stream>>>(
        xhi, nullptr, Whi + 2 * (size_t)EE * EE, nullptr, nullptr, nullptr, bv, nullptr,
        nullptr, nullptr, nullptr, v_sd, nullptr, nullptr, M, EE, EE);

    transpose_v<<<dim3(SS / 64, BB * HH), 256, 0, stream>>>(v_sd, vt);

    yat_attn_mfma<<<dim3(SS / 64, BB * HH, 2), 256, 0, stream>>>(
        qhi, qlo, khi, vt, sqn, skn, alpha, Opart, mlpart);

    combine_attn<<<RR * 16 / 256, 256, 0, stream>>>(Opart, mlpart, ctxhi);

    // O projection: plain bf16 (error ~6e-4 ≪ threshold)
    gemm3p<0, 1><<<dim3(EE / 128, M / 128), 256, 0, stream>>>(
        ctxhi, nullptr, Wohi, nullptr, bo, nullptr, nullptr, out,
        nullptr, nullptr, nullptr, nullptr, nullptr, nullptr, M, EE, EE);
}